// Round 5
// baseline (136.039 us; speedup 1.0000x reference)
//
#include <hip/hip_runtime.h>

// MWPT: 3-level wavelet packet, KS=8, circular pad(3,3), stride-2.
// y[n] = sum_k x[(2n+k-3) mod T] * w[k];  hi[j] = (-1)^j * ker[7-j]
//
// CHUNK = 4096 x-samples per block, level-by-level through LDS.
// R5 = R4 with ext_vector types for __builtin_nontemporal_store
// (HIP float4/float2 are class types; the builtin requires real vectors).
//   - ALL global stores deferred past the last barrier (no s_barrier ever
//     drains vmcnt on an output store).
//   - Output stores nontemporal (output never re-read; keep x in cache).
//
// Output layout (flat, fp32):
//   level1 [128][2][32768]  @ 0          order [a0, a4]
//   level2 [128][4][16384]  @ 8388608    order [b0, b2, b6, b4]
//   level3 [128][8][8192]   @ 16777216   order [c0, c1, c3, c2, c6, c7, c5, c4]

#define T_MASK 65535
#define P(i)   ((i) + ((i) >> 4))

typedef float vf4 __attribute__((ext_vector_type(4)));
typedef float vf2 __attribute__((ext_vector_type(2)));

#define XS_N 4144                 // x local i <-> x[(A + i) mod T], A = 4096*seg - 24
#define AS_N 2066                 // a local jj <-> a[N1 - 9 + jj]
#define BS_N 1030                 // b local m  <-> b[N2 - 3 + m]
#define XS_P (P(XS_N - 1) + 1)    // 4402
#define AS_P (P(AS_N - 1) + 1)    // 2195
#define BS_P (P(BS_N - 1) + 1)    // 1094 ; 4*1094 = 4376 <= XS_P (reuse)

__global__ __launch_bounds__(256) void mwpt_kernel(
    const float* __restrict__ x, const float* __restrict__ ker,
    float* __restrict__ out)
{
    __shared__ float lds[XS_P + 2 * AS_P];    // 8792 floats = 35.2 KB
    float* xs  = lds;
    float* as0 = lds + XS_P;
    float* as1 = lds + XS_P + AS_P;
    float* bs0 = lds;                          // xs region reused after L1
    float* bs1 = lds + BS_P;
    float* bs2 = lds + 2 * BS_P;
    float* bs3 = lds + 3 * BS_P;

    const int t   = threadIdx.x;
    const int seg = blockIdx.x;                // 0..15
    const int bi  = blockIdx.y;                // 0..127
    const int N1  = seg * 2048;
    const int N2  = seg * 1024;
    const int N3  = seg * 512;
    const float* __restrict__ xrow = x + (size_t)bi * 65536;

    float lo[8], hi[8];
#pragma unroll
    for (int k = 0; k < 8; ++k) lo[k] = ker[k];
#pragma unroll
    for (int k = 0; k < 8; ++k) hi[k] = (k & 1) ? -ker[7 - k] : ker[7 - k];

    // ---- stage x: 1036 aligned float4 loads (wrap-safe: A%4==0, no cross) ----
    const int A = 4096 * seg - 24;
    for (int u = t; u < 1036; u += 256) {
        int g = (A + 4 * u) & T_MASK;
        vf4 v = *(const vf4*)(xrow + g);
        int ip = P(4 * u);                     // 4u%16 in {0,4,8,12}: contiguous
        xs[ip] = v.x; xs[ip + 1] = v.y; xs[ip + 2] = v.z; xs[ip + 3] = v.w;
    }

    __syncthreads();

    // ---- level 1: a[jj] = sum_k xs[2*jj + 3 + k] * w ; main jj = 8t+9..8t+16 ----
    float r0[8], r4[8];
    {
        float xv[22];
#pragma unroll
        for (int q = 0; q < 22; ++q) xv[q] = xs[P(16 * t + 21 + q)];
#pragma unroll
        for (int i = 0; i < 8; ++i) {
            float s0 = 0.f, s4 = 0.f;
#pragma unroll
            for (int k = 0; k < 8; ++k) {
                float v = xv[2 * i + k];
                s0 += v * lo[k]; s4 += v * hi[k];
            }
            r0[i] = s0; r4[i] = s4;
        }
#pragma unroll
        for (int i = 0; i < 8; ++i) {
            as0[P(8 * t + 9 + i)] = r0[i];
            as1[P(8 * t + 9 + i)] = r4[i];
        }
        if (t < 18) {                          // halo jj in [0,8] u [2057,2065]
            int jj = (t < 9) ? t : (2048 + t);
            float s0 = 0.f, s4 = 0.f;
#pragma unroll
            for (int k = 0; k < 8; ++k) {
                float v = xs[P(2 * jj + 3 + k)];
                s0 += v * lo[k]; s4 += v * hi[k];
            }
            as0[P(jj)] = s0; as1[P(jj)] = s4;
        }
    }

    __syncthreads();

    // ---- level 2: b[m] = sum_k as[2m + k] * w ; main m = 4t+3..4t+6 ----
    float v0[4], v2[4], v4[4], v6[4];
    {
        float av0[14], av1[14];
#pragma unroll
        for (int q = 0; q < 14; ++q) {
            av0[q] = as0[P(8 * t + 6 + q)];
            av1[q] = as1[P(8 * t + 6 + q)];
        }
#pragma unroll
        for (int i = 0; i < 4; ++i) {
            float s0 = 0.f, s2 = 0.f, s4 = 0.f, s6 = 0.f;
#pragma unroll
            for (int k = 0; k < 8; ++k) {
                float a0 = av0[2 * i + k], a4 = av1[2 * i + k];
                s0 += a0 * lo[k]; s2 += a0 * hi[k];
                s4 += a4 * lo[k]; s6 += a4 * hi[k];
            }
            v0[i] = s0; v2[i] = s2; v4[i] = s4; v6[i] = s6;
        }
#pragma unroll
        for (int i = 0; i < 4; ++i) {
            int m = 4 * t + 3 + i;
            bs0[P(m)] = v0[i]; bs1[P(m)] = v2[i];
            bs2[P(m)] = v4[i]; bs3[P(m)] = v6[i];
        }
        if (t < 6) {                           // halo m in [0,2] u [1027,1029]
            int m = (t < 3) ? t : (1024 + t);
            float s0 = 0.f, s2 = 0.f, s4 = 0.f, s6 = 0.f;
#pragma unroll
            for (int k = 0; k < 8; ++k) {
                float a0 = as0[P(2 * m + k)], a4 = as1[P(2 * m + k)];
                s0 += a0 * lo[k]; s2 += a0 * hi[k];
                s4 += a4 * lo[k]; s6 += a4 * hi[k];
            }
            bs0[P(m)] = s0; bs1[P(m)] = s2;
            bs2[P(m)] = s4; bs3[P(m)] = s6;
        }
    }

    __syncthreads();

    // ---- level 3: c[n3] = sum_k bs[2(n3-N3) + k] * w ; n3 = N3 + 2t + {0,1} ----
    float c0[2], c1[2], c2[2], c3[2], c4[2], c5[2], c6[2], c7[2];
    {
        float bv0[10], bv1[10], bv2[10], bv3[10];
#pragma unroll
        for (int q = 0; q < 10; ++q) {
            bv0[q] = bs0[P(4 * t + q)];
            bv1[q] = bs1[P(4 * t + q)];
            bv2[q] = bs2[P(4 * t + q)];
            bv3[q] = bs3[P(4 * t + q)];
        }
#pragma unroll
        for (int j = 0; j < 2; ++j) {
            float s0 = 0.f, s1 = 0.f, s2 = 0.f, s3 = 0.f;
            float s4 = 0.f, s5 = 0.f, s6 = 0.f, s7 = 0.f;
#pragma unroll
            for (int k = 0; k < 8; ++k) {
                float b0 = bv0[2 * j + k], b2 = bv1[2 * j + k];
                float b4 = bv2[2 * j + k], b6 = bv3[2 * j + k];
                s0 += b0 * lo[k]; s1 += b0 * hi[k];
                s2 += b2 * lo[k]; s3 += b2 * hi[k];
                s4 += b4 * lo[k]; s5 += b4 * hi[k];
                s6 += b6 * lo[k]; s7 += b6 * hi[k];
            }
            c0[j] = s0; c1[j] = s1; c2[j] = s2; c3[j] = s3;
            c4[j] = s4; c5[j] = s5; c6[j] = s6; c7[j] = s7;
        }
    }

    // ---- all global stores, nontemporal, after the last barrier ----
    {
        size_t o = (size_t)bi * 65536 + (size_t)N1 + 8 * (size_t)t;
        vf4 w0 = {r0[0], r0[1], r0[2], r0[3]};
        vf4 w1 = {r0[4], r0[5], r0[6], r0[7]};
        vf4 w2 = {r4[0], r4[1], r4[2], r4[3]};
        vf4 w3 = {r4[4], r4[5], r4[6], r4[7]};
        __builtin_nontemporal_store(w0, (vf4*)(out + o));
        __builtin_nontemporal_store(w1, (vf4*)(out + o + 4));
        __builtin_nontemporal_store(w2, (vf4*)(out + o + 32768));
        __builtin_nontemporal_store(w3, (vf4*)(out + o + 32768 + 4));
    }
    {
        // order [b0, b2, b6, b4]
        size_t o = 8388608ull + (size_t)bi * 65536 + (size_t)N2 + 4 * (size_t)t;
        vf4 w0 = {v0[0], v0[1], v0[2], v0[3]};
        vf4 w1 = {v2[0], v2[1], v2[2], v2[3]};
        vf4 w2 = {v6[0], v6[1], v6[2], v6[3]};
        vf4 w3 = {v4[0], v4[1], v4[2], v4[3]};
        __builtin_nontemporal_store(w0, (vf4*)(out + o));
        __builtin_nontemporal_store(w1, (vf4*)(out + o + 16384));
        __builtin_nontemporal_store(w2, (vf4*)(out + o + 2 * 16384));
        __builtin_nontemporal_store(w3, (vf4*)(out + o + 3 * 16384));
    }
    {
        // order [c0, c1, c3, c2, c6, c7, c5, c4]
        size_t o = 16777216ull + (size_t)bi * 65536 + (size_t)N3 + 2 * (size_t)t;
        vf2 w0 = {c0[0], c0[1]};
        vf2 w1 = {c1[0], c1[1]};
        vf2 w2 = {c3[0], c3[1]};
        vf2 w3 = {c2[0], c2[1]};
        vf2 w4 = {c6[0], c6[1]};
        vf2 w5 = {c7[0], c7[1]};
        vf2 w6 = {c5[0], c5[1]};
        vf2 w7 = {c4[0], c4[1]};
        __builtin_nontemporal_store(w0, (vf2*)(out + o));
        __builtin_nontemporal_store(w1, (vf2*)(out + o + 8192));
        __builtin_nontemporal_store(w2, (vf2*)(out + o + 2 * 8192));
        __builtin_nontemporal_store(w3, (vf2*)(out + o + 3 * 8192));
        __builtin_nontemporal_store(w4, (vf2*)(out + o + 4 * 8192));
        __builtin_nontemporal_store(w5, (vf2*)(out + o + 5 * 8192));
        __builtin_nontemporal_store(w6, (vf2*)(out + o + 6 * 8192));
        __builtin_nontemporal_store(w7, (vf2*)(out + o + 7 * 8192));
    }
}

extern "C" void kernel_launch(void* const* d_in, const int* in_sizes, int n_in,
                              void* d_out, int out_size, void* d_ws, size_t ws_size,
                              hipStream_t stream) {
    const float* x   = (const float*)d_in[0];
    const float* ker = (const float*)d_in[1];
    float* out = (float*)d_out;
    dim3 grid(16, 128), block(256);
    hipLaunchKernelGGL(mwpt_kernel, grid, block, 0, stream, x, ker, out);
}

// Round 6
// 128.937 us; speedup vs baseline: 1.0551x; 1.0551x over previous
//
#include <hip/hip_runtime.h>

// MWPT: 3-level wavelet packet, KS=8, circular pad(3,3), stride-2.
// y[n] = sum_k x[(2n+k-3) mod T] * w[k];  hi[j] = (-1)^j * ker[7-j]
//
// R6: single-wave workgroups. CHUNK = 1024 x-samples, 64 threads (1 wave),
// grid 64x128. __syncthreads in a 1-wave block is barrier-free (waitcnt
// only), so no phase lock-step across co-resident waves; LDS 9.1 KB/block
// -> ~16 blocks/CU of independent stagger -> smooth store issue.
// Store widths identical to R3 (2x float4 L1, float4 L2, float2 L3),
// in-place plain stores (R5's NT+deferral regressed).
//
// Output layout (flat, fp32):
//   level1 [128][2][32768]  @ 0          order [a0, a4]
//   level2 [128][4][16384]  @ 8388608    order [b0, b2, b6, b4]
//   level3 [128][8][8192]   @ 16777216   order [c0, c1, c3, c2, c6, c7, c5, c4]

#define T_MASK 65535
#define P(i)   ((i) + ((i) >> 4))

#define XS_N 1072                 // x local i <-> x[(A + i) mod T], A = 1024*seg - 24
#define AS_N 530                  // a local jj <-> a[N1 - 9 + jj]
#define BS_N 262                  // b local m  <-> b[N2 - 3 + m]
#define XS_P (P(XS_N - 1) + 1)    // 1138
#define AS_P (P(AS_N - 1) + 1)    // 563
#define BS_P (P(BS_N - 1) + 1)    // 278 ; 4*278 = 1112 <= XS_P (reuse)

__global__ __launch_bounds__(64) void mwpt_kernel(
    const float* __restrict__ x, const float* __restrict__ ker,
    float* __restrict__ out)
{
    __shared__ float lds[XS_P + 2 * AS_P];    // 2264 floats = 9.1 KB
    float* xs  = lds;
    float* as0 = lds + XS_P;
    float* as1 = lds + XS_P + AS_P;
    float* bs0 = lds;                          // xs region reused after L1
    float* bs1 = lds + BS_P;
    float* bs2 = lds + 2 * BS_P;
    float* bs3 = lds + 3 * BS_P;

    const int t   = threadIdx.x;               // 0..63
    const int seg = blockIdx.x;                // 0..63
    const int bi  = blockIdx.y;                // 0..127
    const int N1  = seg * 512;
    const int N2  = seg * 256;
    const int N3  = seg * 128;
    const float* __restrict__ xrow = x + (size_t)bi * 65536;

    float lo[8], hi[8];
#pragma unroll
    for (int k = 0; k < 8; ++k) lo[k] = ker[k];
#pragma unroll
    for (int k = 0; k < 8; ++k) hi[k] = (k & 1) ? -ker[7 - k] : ker[7 - k];

    // ---- stage x: 268 aligned float4 loads (A%4==0, no 16B wrap-cross) ----
    const int A = 1024 * seg - 24;
    for (int u = t; u < 268; u += 64) {
        int g = (A + 4 * u) & T_MASK;
        float4 v = *(const float4*)(xrow + g);
        int ip = P(4 * u);                     // 4u%16 in {0,4,8,12}: contiguous
        xs[ip] = v.x; xs[ip + 1] = v.y; xs[ip + 2] = v.z; xs[ip + 3] = v.w;
    }

    __syncthreads();                           // 1 wave: waitcnt only

    // ---- level 1: a[jj] = sum_k xs[2*jj + 3 + k] * w ; main jj = 8t+9..8t+16 ----
    {
        float xv[22];
#pragma unroll
        for (int q = 0; q < 22; ++q) xv[q] = xs[P(16 * t + 21 + q)];
        float r0[8], r4[8];
#pragma unroll
        for (int i = 0; i < 8; ++i) {
            float s0 = 0.f, s4 = 0.f;
#pragma unroll
            for (int k = 0; k < 8; ++k) {
                float v = xv[2 * i + k];
                s0 += v * lo[k]; s4 += v * hi[k];
            }
            r0[i] = s0; r4[i] = s4;
        }
#pragma unroll
        for (int i = 0; i < 8; ++i) {
            as0[P(8 * t + 9 + i)] = r0[i];
            as1[P(8 * t + 9 + i)] = r4[i];
        }
        if (t < 18) {                          // halo jj in [0,8] u [521,529]
            int jj = (t < 9) ? t : (512 + t);
            float s0 = 0.f, s4 = 0.f;
#pragma unroll
            for (int k = 0; k < 8; ++k) {
                float v = xs[P(2 * jj + 3 + k)];
                s0 += v * lo[k]; s4 += v * hi[k];
            }
            as0[P(jj)] = s0; as1[P(jj)] = s4;
        }
        size_t o = (size_t)bi * 65536 + (size_t)N1 + 8 * (size_t)t;
        *(float4*)(out + o)             = make_float4(r0[0], r0[1], r0[2], r0[3]);
        *(float4*)(out + o + 4)         = make_float4(r0[4], r0[5], r0[6], r0[7]);
        *(float4*)(out + o + 32768)     = make_float4(r4[0], r4[1], r4[2], r4[3]);
        *(float4*)(out + o + 32768 + 4) = make_float4(r4[4], r4[5], r4[6], r4[7]);
    }

    __syncthreads();

    // ---- level 2: b[m] = sum_k as[2m + k] * w ; main m = 4t+3..4t+6 ----
    {
        float av0[14], av1[14];
#pragma unroll
        for (int q = 0; q < 14; ++q) {
            av0[q] = as0[P(8 * t + 6 + q)];
            av1[q] = as1[P(8 * t + 6 + q)];
        }
        float v0[4], v2[4], v4[4], v6[4];
#pragma unroll
        for (int i = 0; i < 4; ++i) {
            float s0 = 0.f, s2 = 0.f, s4 = 0.f, s6 = 0.f;
#pragma unroll
            for (int k = 0; k < 8; ++k) {
                float a0 = av0[2 * i + k], a4 = av1[2 * i + k];
                s0 += a0 * lo[k]; s2 += a0 * hi[k];
                s4 += a4 * lo[k]; s6 += a4 * hi[k];
            }
            v0[i] = s0; v2[i] = s2; v4[i] = s4; v6[i] = s6;
        }
#pragma unroll
        for (int i = 0; i < 4; ++i) {
            int m = 4 * t + 3 + i;
            bs0[P(m)] = v0[i]; bs1[P(m)] = v2[i];
            bs2[P(m)] = v4[i]; bs3[P(m)] = v6[i];
        }
        if (t < 6) {                           // halo m in [0,2] u [259,261]
            int m = (t < 3) ? t : (256 + t);
            float s0 = 0.f, s2 = 0.f, s4 = 0.f, s6 = 0.f;
#pragma unroll
            for (int k = 0; k < 8; ++k) {
                float a0 = as0[P(2 * m + k)], a4 = as1[P(2 * m + k)];
                s0 += a0 * lo[k]; s2 += a0 * hi[k];
                s4 += a4 * lo[k]; s6 += a4 * hi[k];
            }
            bs0[P(m)] = s0; bs1[P(m)] = s2;
            bs2[P(m)] = s4; bs3[P(m)] = s6;
        }
        // order [b0, b2, b6, b4]
        size_t o = 8388608ull + (size_t)bi * 65536 + (size_t)N2 + 4 * (size_t)t;
        *(float4*)(out + o)             = make_float4(v0[0], v0[1], v0[2], v0[3]);
        *(float4*)(out + o + 16384)     = make_float4(v2[0], v2[1], v2[2], v2[3]);
        *(float4*)(out + o + 2 * 16384) = make_float4(v6[0], v6[1], v6[2], v6[3]);
        *(float4*)(out + o + 3 * 16384) = make_float4(v4[0], v4[1], v4[2], v4[3]);
    }

    __syncthreads();

    // ---- level 3: c[n3] = sum_k bs[2(n3-N3) + k] * w ; n3 = N3 + 2t + {0,1} ----
    {
        float bv0[10], bv1[10], bv2[10], bv3[10];
#pragma unroll
        for (int q = 0; q < 10; ++q) {
            bv0[q] = bs0[P(4 * t + q)];
            bv1[q] = bs1[P(4 * t + q)];
            bv2[q] = bs2[P(4 * t + q)];
            bv3[q] = bs3[P(4 * t + q)];
        }
        float c0[2], c1[2], c2[2], c3[2], c4[2], c5[2], c6[2], c7[2];
#pragma unroll
        for (int j = 0; j < 2; ++j) {
            float s0 = 0.f, s1 = 0.f, s2 = 0.f, s3 = 0.f;
            float s4 = 0.f, s5 = 0.f, s6 = 0.f, s7 = 0.f;
#pragma unroll
            for (int k = 0; k < 8; ++k) {
                float b0 = bv0[2 * j + k], b2 = bv1[2 * j + k];
                float b4 = bv2[2 * j + k], b6 = bv3[2 * j + k];
                s0 += b0 * lo[k]; s1 += b0 * hi[k];
                s2 += b2 * lo[k]; s3 += b2 * hi[k];
                s4 += b4 * lo[k]; s5 += b4 * hi[k];
                s6 += b6 * lo[k]; s7 += b6 * hi[k];
            }
            c0[j] = s0; c1[j] = s1; c2[j] = s2; c3[j] = s3;
            c4[j] = s4; c5[j] = s5; c6[j] = s6; c7[j] = s7;
        }
        // order [c0, c1, c3, c2, c6, c7, c5, c4]
        size_t o = 16777216ull + (size_t)bi * 65536 + (size_t)N3 + 2 * (size_t)t;
        *(float2*)(out + o)            = make_float2(c0[0], c0[1]);
        *(float2*)(out + o + 8192)     = make_float2(c1[0], c1[1]);
        *(float2*)(out + o + 2 * 8192) = make_float2(c3[0], c3[1]);
        *(float2*)(out + o + 3 * 8192) = make_float2(c2[0], c2[1]);
        *(float2*)(out + o + 4 * 8192) = make_float2(c6[0], c6[1]);
        *(float2*)(out + o + 5 * 8192) = make_float2(c7[0], c7[1]);
        *(float2*)(out + o + 6 * 8192) = make_float2(c5[0], c5[1]);
        *(float2*)(out + o + 7 * 8192) = make_float2(c4[0], c4[1]);
    }
}

extern "C" void kernel_launch(void* const* d_in, const int* in_sizes, int n_in,
                              void* d_out, int out_size, void* d_ws, size_t ws_size,
                              hipStream_t stream) {
    const float* x   = (const float*)d_in[0];
    const float* ker = (const float*)d_in[1];
    float* out = (float*)d_out;
    dim3 grid(64, 128), block(64);
    hipLaunchKernelGGL(mwpt_kernel, grid, block, 0, stream, x, ker, out);
}